// Round 2
// baseline (16420.001 us; speedup 1.0000x reference)
//
#include <hip/hip_runtime.h>

#define NCAM 6
#define DD 118
#define FHH 32
#define FWW 88
#define CC 80
#define NXV 360
#define NYV 360
#define NVOX (NXV * NYV)                      /* 129600 */
#define PTS_PER_CAM (DD * FHH * FWW)          /* 332288 */
#define NPTS (NCAM * PTS_PER_CAM)             /* 1993728 */
#define BLK 256
#define BLOCKS_PER_CAM (PTS_PER_CAM / BLK)    /* 1298, exact */

// inverse of row-major 3x3 in double
__device__ __forceinline__ void inv3x3d(const double* m, double* inv) {
    double c00 = m[4] * m[8] - m[5] * m[7];
    double c01 = m[3] * m[8] - m[5] * m[6];
    double c02 = m[3] * m[7] - m[4] * m[6];
    double det = m[0] * c00 - m[1] * c01 + m[2] * c02;
    double id  = 1.0 / det;
    inv[0] =  c00 * id;
    inv[1] = (m[2] * m[7] - m[1] * m[8]) * id;
    inv[2] = (m[1] * m[5] - m[2] * m[4]) * id;
    inv[3] = -c01 * id;
    inv[4] = (m[0] * m[8] - m[2] * m[6]) * id;
    inv[5] = (m[2] * m[3] - m[0] * m[5]) * id;
    inv[6] =  c02 * id;
    inv[7] = (m[1] * m[6] - m[0] * m[7]) * id;
    inv[8] = (m[0] * m[4] - m[1] * m[3]) * id;
}

// Per-camera parameter pack, 48 floats (see round 0 comment)
__global__ void precomp_kernel(const float* __restrict__ c2e,
                               const float* __restrict__ l2e,
                               const float* __restrict__ intr,
                               const float* __restrict__ aug,
                               const float* __restrict__ laug,
                               float* __restrict__ P) {
    int n = threadIdx.x;
    if (n >= NCAM) return;
    double rots[9], intrins[9], post[9], l2er[9], er[9];
    double trans[3], ptrans[3], l2et[3], et[3];
    for (int i = 0; i < 3; i++) {
        for (int j = 0; j < 3; j++) {
            rots[i * 3 + j]    = c2e[n * 16 + i * 4 + j];
            intrins[i * 3 + j] = intr[n * 16 + i * 4 + j];
            post[i * 3 + j]    = aug[n * 16 + i * 4 + j];
            l2er[i * 3 + j]    = l2e[i * 4 + j];
            er[i * 3 + j]      = laug[i * 4 + j];
        }
        trans[i]  = c2e[n * 16 + i * 4 + 3];
        ptrans[i] = aug[n * 16 + i * 4 + 3];
        l2et[i]   = l2e[i * 4 + 3];
        et[i]     = laug[i * 4 + 3];
    }
    double A[9], IC[9], L[9], Cm[9];
    inv3x3d(post, A);
    inv3x3d(intrins, IC);
    inv3x3d(l2er, L);
    for (int i = 0; i < 3; i++)
        for (int j = 0; j < 3; j++)
            Cm[i * 3 + j] = rots[i * 3 + 0] * IC[0 + j] +
                            rots[i * 3 + 1] * IC[3 + j] +
                            rots[i * 3 + 2] * IC[6 + j];
    float* p = P + n * 48;
    for (int k = 0; k < 9; k++) p[k]      = (float)A[k];
    for (int k = 0; k < 3; k++) p[9 + k]  = (float)ptrans[k];
    for (int k = 0; k < 9; k++) p[12 + k] = (float)Cm[k];
    for (int k = 0; k < 3; k++) p[21 + k] = (float)trans[k];
    for (int k = 0; k < 3; k++) p[24 + k] = (float)l2et[k];
    for (int k = 0; k < 9; k++) p[27 + k] = (float)L[k];
    for (int k = 0; k < 9; k++) p[36 + k] = (float)er[k];
    for (int k = 0; k < 3; k++) p[45 + k] = (float)et[k];
}

// Phase 1: geometry -> push kept point onto per-voxel linked list.
__global__ __launch_bounds__(BLK) void geom_kernel(
        const float* __restrict__ P,
        int* __restrict__ head,
        int* __restrict__ nxt) {
    int cam   = blockIdx.x / BLOCKS_PER_CAM;          // wave-uniform
    int local = (blockIdx.x % BLOCKS_PER_CAM) * BLK + threadIdx.x;
    int d   = local / (FHH * FWW);
    int rem = local - d * (FHH * FWW);
    int h   = rem / FWW;
    int w   = rem - h * FWW;

    const float* p = P + cam * 48;

    float fx = (float)((double)w * (703.0 / 87.0));   // linspace(0, 703, 88)
    float fy = (float)((double)h * (255.0 / 31.0));   // linspace(0, 255, 32)
    float fd = 1.0f + 0.5f * (float)d;                // arange(1, 60, 0.5)

    float vx = fx - p[9], vy = fy - p[10], vz = fd - p[11];
    float qx = p[0] * vx + p[1] * vy + p[2] * vz;
    float qy = p[3] * vx + p[4] * vy + p[5] * vz;
    float qz = p[6] * vx + p[7] * vy + p[8] * vz;
    float px = qx * qz, py = qy * qz, pz = qz;
    float rx = p[12] * px + p[13] * py + p[14] * pz + p[21];
    float ry = p[15] * px + p[16] * py + p[17] * pz + p[22];
    float rz = p[18] * px + p[19] * py + p[20] * pz + p[23];
    rx -= p[24]; ry -= p[25]; rz -= p[26];
    float sx = p[27] * rx + p[28] * ry + p[29] * rz;
    float sy = p[30] * rx + p[31] * ry + p[32] * rz;
    float sz = p[33] * rx + p[34] * ry + p[35] * rz;
    float gx = p[36] * sx + p[37] * sy + p[38] * sz + p[45];
    float gy = p[39] * sx + p[40] * sy + p[41] * sz + p[46];
    float gz = p[42] * sx + p[43] * sy + p[44] * sz + p[47];

    const float offx = (-54.0f + 0.15f) - 0.15f;
    const float offy = (-54.0f + 0.15f) - 0.15f;
    const float offz = -10.0f;

    int cx = (int)((gx - offx) / 0.3f);
    int cy = (int)((gy - offy) / 0.3f);
    int cz = (int)((gz - offz) / 20.0f);

    bool kept = (cx >= 0) & (cx < NXV) & (cy >= 0) & (cy < NYV) &
                (cz >= 0) & (cz < 1);
    if (!kept) return;

    int vox = cx * NYV + cy;
    int pt  = cam * PTS_PER_CAM + local;
    int old = atomicExch(&head[vox], pt);
    nxt[pt] = old;
}

// Phase 2: one wave gathers 16 consecutive voxels; lanes own channels.
// Stores are full 64B lines per lane (4x float4). Writes zeros for empty
// voxels, so no output memset is needed.
__global__ __launch_bounds__(256) void gather_kernel(
        const float* __restrict__ feats,
        const int* __restrict__ head,
        const int* __restrict__ nxt,
        float* __restrict__ out) {
    int wave = blockIdx.x * 4 + (threadIdx.x >> 6);
    int lane = threadIdx.x & 63;
    int vox0 = wave * 16;

    float acc0[16];
    float acc1[16];
    #pragma unroll
    for (int v = 0; v < 16; v++) { acc0[v] = 0.f; acc1[v] = 0.f; }

    #pragma unroll
    for (int v = 0; v < 16; v++) {
        int pt = head[vox0 + v];
        while (pt >= 0) {
            const float* row = feats + (size_t)pt * CC;
            acc0[v] += row[lane];
            if (lane < 16) acc1[v] += row[64 + lane];
            pt = nxt[pt];
        }
    }

    float* o0 = out + (size_t)lane * NVOX + vox0;   // 64B-aligned run of 16
    #pragma unroll
    for (int v4 = 0; v4 < 4; v4++) {
        float4 t = make_float4(acc0[4 * v4 + 0], acc0[4 * v4 + 1],
                               acc0[4 * v4 + 2], acc0[4 * v4 + 3]);
        ((float4*)o0)[v4] = t;
    }
    if (lane < 16) {
        float* o1 = out + (size_t)(64 + lane) * NVOX + vox0;
        #pragma unroll
        for (int v4 = 0; v4 < 4; v4++) {
            float4 t = make_float4(acc1[4 * v4 + 0], acc1[4 * v4 + 1],
                                   acc1[4 * v4 + 2], acc1[4 * v4 + 3]);
            ((float4*)o1)[v4] = t;
        }
    }
}

extern "C" void kernel_launch(void* const* d_in, const int* in_sizes, int n_in,
                              void* d_out, int out_size, void* d_ws, size_t ws_size,
                              hipStream_t stream) {
    const float* feats = (const float*)d_in[0];
    const float* c2e   = (const float*)d_in[1];
    const float* l2e   = (const float*)d_in[2];
    const float* intr  = (const float*)d_in[3];
    const float* aug   = (const float*)d_in[4];
    const float* laug  = (const float*)d_in[5];
    float* out = (float*)d_out;

    // ws layout: P (6*48 f32, 1152 B, pad to 1536) | head (NVOX int) | next (NPTS int)
    float* P   = (float*)d_ws;
    int* head  = (int*)((char*)d_ws + 1536);
    int* nxt   = (int*)((char*)d_ws + 1536 + sizeof(int) * (size_t)NVOX);

    precomp_kernel<<<1, 64, 0, stream>>>(c2e, l2e, intr, aug, laug, P);
    hipMemsetAsync(head, 0xFF, sizeof(int) * (size_t)NVOX, stream);  // head = -1
    geom_kernel<<<NCAM * BLOCKS_PER_CAM, BLK, 0, stream>>>(P, head, nxt);
    gather_kernel<<<NVOX / 16 / 4, 256, 0, stream>>>(feats, head, nxt, out);
}

// Round 3
// 2222.768 us; speedup vs baseline: 7.3872x; 7.3872x over previous
//
#include <hip/hip_runtime.h>

#define NCAM 6
#define DD 118
#define FHH 32
#define FWW 88
#define CC 80
#define NXV 360
#define NYV 360
#define NVOX (NXV * NYV)                      /* 129600 */
#define PTS_PER_CAM (DD * FHH * FWW)          /* 332288 */
#define NPTS (NCAM * PTS_PER_CAM)             /* 1993728 */
#define BLK 256
#define NPT_BLOCKS (NPTS / BLK)               /* 7788, exact */
#define SCAN_BLOCKS ((NVOX + 255) / 256)      /* 507 */
#define HEAVY_T 256
#define SEG 256
#define MAX_SEGS 8192

// ws byte offsets
#define WS_P      0
#define WS_CNT    1536
#define WS_NSEG   (WS_CNT + NVOX * 4)          /* 519936, 16B region */
#define WS_CURSOR (WS_NSEG + 16)
#define WS_BSUM   (WS_CURSOR + NVOX * 4)       /* 512 ints */
#define WS_SEGS   (WS_BSUM + 2048)             /* int4 x MAX_SEGS */
#define WS_IDX    (WS_SEGS + MAX_SEGS * 16)

// inverse of row-major 3x3 in double
__device__ __forceinline__ void inv3x3d(const double* m, double* inv) {
    double c00 = m[4] * m[8] - m[5] * m[7];
    double c01 = m[3] * m[8] - m[5] * m[6];
    double c02 = m[3] * m[7] - m[4] * m[6];
    double det = m[0] * c00 - m[1] * c01 + m[2] * c02;
    double id  = 1.0 / det;
    inv[0] =  c00 * id;
    inv[1] = (m[2] * m[7] - m[1] * m[8]) * id;
    inv[2] = (m[1] * m[5] - m[2] * m[4]) * id;
    inv[3] = -c01 * id;
    inv[4] = (m[0] * m[8] - m[2] * m[6]) * id;
    inv[5] = (m[2] * m[3] - m[0] * m[5]) * id;
    inv[6] =  c02 * id;
    inv[7] = (m[1] * m[6] - m[0] * m[7]) * id;
    inv[8] = (m[0] * m[4] - m[1] * m[3]) * id;
}

__global__ void precomp_kernel(const float* __restrict__ c2e,
                               const float* __restrict__ l2e,
                               const float* __restrict__ intr,
                               const float* __restrict__ aug,
                               const float* __restrict__ laug,
                               float* __restrict__ P) {
    int n = threadIdx.x;
    if (n >= NCAM) return;
    double rots[9], intrins[9], post[9], l2er[9], er[9];
    double trans[3], ptrans[3], l2et[3], et[3];
    for (int i = 0; i < 3; i++) {
        for (int j = 0; j < 3; j++) {
            rots[i * 3 + j]    = c2e[n * 16 + i * 4 + j];
            intrins[i * 3 + j] = intr[n * 16 + i * 4 + j];
            post[i * 3 + j]    = aug[n * 16 + i * 4 + j];
            l2er[i * 3 + j]    = l2e[i * 4 + j];
            er[i * 3 + j]      = laug[i * 4 + j];
        }
        trans[i]  = c2e[n * 16 + i * 4 + 3];
        ptrans[i] = aug[n * 16 + i * 4 + 3];
        l2et[i]   = l2e[i * 4 + 3];
        et[i]     = laug[i * 4 + 3];
    }
    double A[9], IC[9], L[9], Cm[9];
    inv3x3d(post, A);
    inv3x3d(intrins, IC);
    inv3x3d(l2er, L);
    for (int i = 0; i < 3; i++)
        for (int j = 0; j < 3; j++)
            Cm[i * 3 + j] = rots[i * 3 + 0] * IC[0 + j] +
                            rots[i * 3 + 1] * IC[3 + j] +
                            rots[i * 3 + 2] * IC[6 + j];
    float* p = P + n * 48;
    for (int k = 0; k < 9; k++) p[k]      = (float)A[k];
    for (int k = 0; k < 3; k++) p[9 + k]  = (float)ptrans[k];
    for (int k = 0; k < 9; k++) p[12 + k] = (float)Cm[k];
    for (int k = 0; k < 3; k++) p[21 + k] = (float)trans[k];
    for (int k = 0; k < 3; k++) p[24 + k] = (float)l2et[k];
    for (int k = 0; k < 9; k++) p[27 + k] = (float)L[k];
    for (int k = 0; k < 9; k++) p[36 + k] = (float)er[k];
    for (int k = 0; k < 3; k++) p[45 + k] = (float)et[k];
}

// geometry -> voxel id (or -1). Deterministic: identical code in count & fill.
__device__ __forceinline__ int point_voxel(const float* __restrict__ P, int gid) {
    int cam   = gid / PTS_PER_CAM;
    int local = gid - cam * PTS_PER_CAM;
    int d   = local / (FHH * FWW);
    int rem = local - d * (FHH * FWW);
    int h   = rem / FWW;
    int w   = rem - h * FWW;
    const float* p = P + cam * 48;

    float fx = (float)((double)w * (703.0 / 87.0));
    float fy = (float)((double)h * (255.0 / 31.0));
    float fd = 1.0f + 0.5f * (float)d;

    float vx = fx - p[9], vy = fy - p[10], vz = fd - p[11];
    float qx = p[0] * vx + p[1] * vy + p[2] * vz;
    float qy = p[3] * vx + p[4] * vy + p[5] * vz;
    float qz = p[6] * vx + p[7] * vy + p[8] * vz;
    float px = qx * qz, py = qy * qz, pz = qz;
    float rx = p[12] * px + p[13] * py + p[14] * pz + p[21];
    float ry = p[15] * px + p[16] * py + p[17] * pz + p[22];
    float rz = p[18] * px + p[19] * py + p[20] * pz + p[23];
    rx -= p[24]; ry -= p[25]; rz -= p[26];
    float sx = p[27] * rx + p[28] * ry + p[29] * rz;
    float sy = p[30] * rx + p[31] * ry + p[32] * rz;
    float sz = p[33] * rx + p[34] * ry + p[35] * rz;
    float gx = p[36] * sx + p[37] * sy + p[38] * sz + p[45];
    float gy = p[39] * sx + p[40] * sy + p[41] * sz + p[46];
    float gz = p[42] * sx + p[43] * sy + p[44] * sz + p[47];

    const float offx = (-54.0f + 0.15f) - 0.15f;
    const float offy = (-54.0f + 0.15f) - 0.15f;
    const float offz = -10.0f;
    int cx = (int)((gx - offx) / 0.3f);
    int cy = (int)((gy - offy) / 0.3f);
    int cz = (int)((gz - offz) / 20.0f);
    bool kept = (cx >= 0) & (cx < NXV) & (cy >= 0) & (cy < NYV) &
                (cz >= 0) & (cz < 1);
    return kept ? (cx * NYV + cy) : -1;
}

__global__ __launch_bounds__(BLK) void geom_count_kernel(
        const float* __restrict__ P, int* __restrict__ cnt) {
    int gid = blockIdx.x * BLK + threadIdx.x;
    int vox = point_voxel(P, gid);
    if (vox >= 0) atomicAdd(&cnt[vox], 1);
}

// ---- exclusive scan of cnt[NVOX] into cursor[NVOX] (3 kernels) ----
__global__ __launch_bounds__(256) void scan1_kernel(
        const int* __restrict__ cnt, int* __restrict__ cursor,
        int* __restrict__ bsum) {
    __shared__ int sh[256];
    int tid = threadIdx.x;
    int i = blockIdx.x * 256 + tid;
    int v = (i < NVOX) ? cnt[i] : 0;
    sh[tid] = v;
    __syncthreads();
    for (int o = 1; o < 256; o <<= 1) {
        int t = (tid >= o) ? sh[tid - o] : 0;
        __syncthreads();
        sh[tid] += t;
        __syncthreads();
    }
    int incl = sh[tid];
    if (i < NVOX) cursor[i] = incl - v;
    if (tid == 255) bsum[blockIdx.x] = incl;
}

__global__ __launch_bounds__(512) void scan2_kernel(int* __restrict__ bsum) {
    __shared__ int sh[512];
    int tid = threadIdx.x;
    int v = (tid < SCAN_BLOCKS) ? bsum[tid] : 0;
    sh[tid] = v;
    __syncthreads();
    for (int o = 1; o < 512; o <<= 1) {
        int t = (tid >= o) ? sh[tid - o] : 0;
        __syncthreads();
        sh[tid] += t;
        __syncthreads();
    }
    if (tid < SCAN_BLOCKS) bsum[tid] = sh[tid] - v;  // exclusive
}

__global__ __launch_bounds__(256) void scan3_kernel(
        int* __restrict__ cursor, const int* __restrict__ bsum) {
    int i = blockIdx.x * 256 + threadIdx.x;
    if (i < NVOX) cursor[i] += bsum[blockIdx.x];
}

// ---- heavy-voxel segment worklist (cursor still = exclusive offsets) ----
__global__ __launch_bounds__(256) void buildsegs_kernel(
        const int* __restrict__ cnt, const int* __restrict__ cursor,
        int* __restrict__ nseg, int4* __restrict__ segs) {
    int v = blockIdx.x * 256 + threadIdx.x;
    if (v >= NVOX) return;
    int c = cnt[v];
    if (c <= HEAVY_T) return;
    int ns = (c + SEG - 1) / SEG;
    int base = atomicAdd(nseg, ns);
    int off0 = cursor[v];
    for (int k = 0; k < ns; k++) {
        if (base + k < MAX_SEGS) {
            int len = min(SEG, c - k * SEG);
            segs[base + k] = make_int4(v, off0 + k * SEG, len, 0);
        }
    }
}

// ---- fill CSR: cursor becomes inclusive end offsets ----
__global__ __launch_bounds__(BLK) void fill_kernel(
        const float* __restrict__ P, int* __restrict__ cursor,
        int* __restrict__ idx) {
    int gid = blockIdx.x * BLK + threadIdx.x;
    int vox = point_voxel(P, gid);
    if (vox >= 0) {
        int p = atomicAdd(&cursor[vox], 1);
        idx[p] = gid;
    }
}

// ---- light gather: wave per 16 voxels, lanes own channels ----
__global__ __launch_bounds__(256) void light_kernel(
        const float* __restrict__ feats,
        const int* __restrict__ cnt,
        const int* __restrict__ cursor,   // inclusive end offsets
        const int* __restrict__ idx,
        float* __restrict__ out) {
    int wave = blockIdx.x * 4 + (threadIdx.x >> 6);
    int lane = threadIdx.x & 63;
    int vox0 = wave * 16;

    float acc0[16];
    float acc1[16];
    #pragma unroll
    for (int v = 0; v < 16; v++) { acc0[v] = 0.f; acc1[v] = 0.f; }

    for (int v = 0; v < 16; v++) {
        int gvox = vox0 + v;
        int c = cnt[gvox];
        if (c == 0 || c > HEAVY_T) continue;   // heavy handled elsewhere
        int end   = cursor[gvox];
        int start = end - c;
        int i = start;
        for (; i + 1 < end; i += 2) {
            int pt0 = idx[i], pt1 = idx[i + 1];
            const float* r0 = feats + (size_t)pt0 * CC;
            const float* r1 = feats + (size_t)pt1 * CC;
            float a0 = r0[lane];
            float a1 = r1[lane];
            float b0 = 0.f, b1 = 0.f;
            if (lane < 16) { b0 = r0[64 + lane]; b1 = r1[64 + lane]; }
            acc0[v] += a0 + a1;
            acc1[v] += b0 + b1;
        }
        if (i < end) {
            int pt = idx[i];
            const float* r = feats + (size_t)pt * CC;
            acc0[v] += r[lane];
            if (lane < 16) acc1[v] += r[64 + lane];
        }
    }

    float* o0 = out + (size_t)lane * NVOX + vox0;
    #pragma unroll
    for (int v4 = 0; v4 < 4; v4++) {
        ((float4*)o0)[v4] = make_float4(acc0[4 * v4 + 0], acc0[4 * v4 + 1],
                                        acc0[4 * v4 + 2], acc0[4 * v4 + 3]);
    }
    if (lane < 16) {
        float* o1 = out + (size_t)(64 + lane) * NVOX + vox0;
        #pragma unroll
        for (int v4 = 0; v4 < 4; v4++) {
            ((float4*)o1)[v4] = make_float4(acc1[4 * v4 + 0], acc1[4 * v4 + 1],
                                            acc1[4 * v4 + 2], acc1[4 * v4 + 3]);
        }
    }
}

// ---- heavy gather: wave per <=256-point segment, 80 atomics per segment ----
__global__ __launch_bounds__(256) void heavy_kernel(
        const float* __restrict__ feats,
        const int* __restrict__ nseg,
        const int4* __restrict__ segs,
        const int* __restrict__ idx,
        float* __restrict__ out) {
    int wave = blockIdx.x * 4 + (threadIdx.x >> 6);
    int lane = threadIdx.x & 63;
    int n = *nseg;
    if (n > MAX_SEGS) n = MAX_SEGS;
    if (wave >= n) return;
    int4 s = segs[wave];
    int vox = s.x, start = s.y, len = s.z;

    float a0 = 0.f, a1 = 0.f;
    int i = 0;
    for (; i + 1 < len; i += 2) {
        int pt0 = idx[start + i], pt1 = idx[start + i + 1];
        const float* r0 = feats + (size_t)pt0 * CC;
        const float* r1 = feats + (size_t)pt1 * CC;
        float x0 = r0[lane];
        float x1 = r1[lane];
        float y0 = 0.f, y1 = 0.f;
        if (lane < 16) { y0 = r0[64 + lane]; y1 = r1[64 + lane]; }
        a0 += x0 + x1;
        a1 += y0 + y1;
    }
    if (i < len) {
        int pt = idx[start + i];
        const float* r = feats + (size_t)pt * CC;
        a0 += r[lane];
        if (lane < 16) a1 += r[64 + lane];
    }
    atomicAdd(&out[(size_t)lane * NVOX + vox], a0);
    if (lane < 16) atomicAdd(&out[(size_t)(64 + lane) * NVOX + vox], a1);
}

extern "C" void kernel_launch(void* const* d_in, const int* in_sizes, int n_in,
                              void* d_out, int out_size, void* d_ws, size_t ws_size,
                              hipStream_t stream) {
    const float* feats = (const float*)d_in[0];
    const float* c2e   = (const float*)d_in[1];
    const float* l2e   = (const float*)d_in[2];
    const float* intr  = (const float*)d_in[3];
    const float* aug   = (const float*)d_in[4];
    const float* laug  = (const float*)d_in[5];
    float* out = (float*)d_out;

    char* ws = (char*)d_ws;
    float* P      = (float*)(ws + WS_P);
    int*   cnt    = (int*)(ws + WS_CNT);
    int*   nseg   = (int*)(ws + WS_NSEG);
    int*   cursor = (int*)(ws + WS_CURSOR);
    int*   bsum   = (int*)(ws + WS_BSUM);
    int4*  segs   = (int4*)(ws + WS_SEGS);
    int*   idx    = (int*)(ws + WS_IDX);

    hipMemsetAsync(cnt, 0, NVOX * 4 + 16, stream);  // cnt + nseg
    precomp_kernel<<<1, 64, 0, stream>>>(c2e, l2e, intr, aug, laug, P);
    geom_count_kernel<<<NPT_BLOCKS, BLK, 0, stream>>>(P, cnt);
    scan1_kernel<<<SCAN_BLOCKS, 256, 0, stream>>>(cnt, cursor, bsum);
    scan2_kernel<<<1, 512, 0, stream>>>(bsum);
    scan3_kernel<<<SCAN_BLOCKS, 256, 0, stream>>>(cursor, bsum);
    buildsegs_kernel<<<SCAN_BLOCKS, 256, 0, stream>>>(cnt, cursor, nseg, segs);
    fill_kernel<<<NPT_BLOCKS, BLK, 0, stream>>>(P, cursor, idx);
    light_kernel<<<NVOX / 16 / 4, 256, 0, stream>>>(feats, cnt, cursor, idx, out);
    heavy_kernel<<<(MAX_SEGS + 3) / 4, 256, 0, stream>>>(feats, nseg, segs, idx, out);
}

// Round 4
// 912.433 us; speedup vs baseline: 17.9958x; 2.4361x over previous
//
#include <hip/hip_runtime.h>

#define NCAM 6
#define DD 118
#define FHH 32
#define FWW 88
#define CC 80
#define NXV 360
#define NYV 360
#define NVOX (NXV * NYV)                      /* 129600 */
#define PTS_PER_CAM (DD * FHH * FWW)          /* 332288 */
#define NPTS (NCAM * PTS_PER_CAM)             /* 1993728 */
#define BLK 256
#define NPT_BLOCKS (NPTS / BLK)               /* 7788, exact */
#define SCAN_BLOCKS ((NVOX + 255) / 256)      /* 507 */
#define SEG 64
#define MAX_SEGS 196608   /* >= 129600 + NPTS/64 = 160752 worst case */

// ws byte offsets
#define WS_P      0
#define WS_CNT    1536
#define WS_NSEG   (WS_CNT + NVOX * 4)
#define WS_CURSOR (WS_NSEG + 16)
#define WS_BSUM   (WS_CURSOR + NVOX * 4)       /* 512 ints */
#define WS_SEGS   (WS_BSUM + 2048)             /* int4 x MAX_SEGS */
#define WS_IDX    (WS_SEGS + MAX_SEGS * 16)    /* NPTS ints */

// inverse of row-major 3x3 in double
__device__ __forceinline__ void inv3x3d(const double* m, double* inv) {
    double c00 = m[4] * m[8] - m[5] * m[7];
    double c01 = m[3] * m[8] - m[5] * m[6];
    double c02 = m[3] * m[7] - m[4] * m[6];
    double det = m[0] * c00 - m[1] * c01 + m[2] * c02;
    double id  = 1.0 / det;
    inv[0] =  c00 * id;
    inv[1] = (m[2] * m[7] - m[1] * m[8]) * id;
    inv[2] = (m[1] * m[5] - m[2] * m[4]) * id;
    inv[3] = -c01 * id;
    inv[4] = (m[0] * m[8] - m[2] * m[6]) * id;
    inv[5] = (m[2] * m[3] - m[0] * m[5]) * id;
    inv[6] =  c02 * id;
    inv[7] = (m[1] * m[6] - m[0] * m[7]) * id;
    inv[8] = (m[0] * m[4] - m[1] * m[3]) * id;
}

__global__ void precomp_kernel(const float* __restrict__ c2e,
                               const float* __restrict__ l2e,
                               const float* __restrict__ intr,
                               const float* __restrict__ aug,
                               const float* __restrict__ laug,
                               float* __restrict__ P) {
    int n = threadIdx.x;
    if (n >= NCAM) return;
    double rots[9], intrins[9], post[9], l2er[9], er[9];
    double trans[3], ptrans[3], l2et[3], et[3];
    for (int i = 0; i < 3; i++) {
        for (int j = 0; j < 3; j++) {
            rots[i * 3 + j]    = c2e[n * 16 + i * 4 + j];
            intrins[i * 3 + j] = intr[n * 16 + i * 4 + j];
            post[i * 3 + j]    = aug[n * 16 + i * 4 + j];
            l2er[i * 3 + j]    = l2e[i * 4 + j];
            er[i * 3 + j]      = laug[i * 4 + j];
        }
        trans[i]  = c2e[n * 16 + i * 4 + 3];
        ptrans[i] = aug[n * 16 + i * 4 + 3];
        l2et[i]   = l2e[i * 4 + 3];
        et[i]     = laug[i * 4 + 3];
    }
    double A[9], IC[9], L[9], Cm[9];
    inv3x3d(post, A);
    inv3x3d(intrins, IC);
    inv3x3d(l2er, L);
    for (int i = 0; i < 3; i++)
        for (int j = 0; j < 3; j++)
            Cm[i * 3 + j] = rots[i * 3 + 0] * IC[0 + j] +
                            rots[i * 3 + 1] * IC[3 + j] +
                            rots[i * 3 + 2] * IC[6 + j];
    float* p = P + n * 48;
    for (int k = 0; k < 9; k++) p[k]      = (float)A[k];
    for (int k = 0; k < 3; k++) p[9 + k]  = (float)ptrans[k];
    for (int k = 0; k < 9; k++) p[12 + k] = (float)Cm[k];
    for (int k = 0; k < 3; k++) p[21 + k] = (float)trans[k];
    for (int k = 0; k < 3; k++) p[24 + k] = (float)l2et[k];
    for (int k = 0; k < 9; k++) p[27 + k] = (float)L[k];
    for (int k = 0; k < 9; k++) p[36 + k] = (float)er[k];
    for (int k = 0; k < 3; k++) p[45 + k] = (float)et[k];
}

// geometry -> voxel id (or -1). Deterministic: identical code in count & fill.
__device__ __forceinline__ int point_voxel(const float* __restrict__ P, int gid) {
    int cam   = gid / PTS_PER_CAM;
    int local = gid - cam * PTS_PER_CAM;
    int d   = local / (FHH * FWW);
    int rem = local - d * (FHH * FWW);
    int h   = rem / FWW;
    int w   = rem - h * FWW;
    const float* p = P + cam * 48;

    float fx = (float)((double)w * (703.0 / 87.0));
    float fy = (float)((double)h * (255.0 / 31.0));
    float fd = 1.0f + 0.5f * (float)d;

    float vx = fx - p[9], vy = fy - p[10], vz = fd - p[11];
    float qx = p[0] * vx + p[1] * vy + p[2] * vz;
    float qy = p[3] * vx + p[4] * vy + p[5] * vz;
    float qz = p[6] * vx + p[7] * vy + p[8] * vz;
    float px = qx * qz, py = qy * qz, pz = qz;
    float rx = p[12] * px + p[13] * py + p[14] * pz + p[21];
    float ry = p[15] * px + p[16] * py + p[17] * pz + p[22];
    float rz = p[18] * px + p[19] * py + p[20] * pz + p[23];
    rx -= p[24]; ry -= p[25]; rz -= p[26];
    float sx = p[27] * rx + p[28] * ry + p[29] * rz;
    float sy = p[30] * rx + p[31] * ry + p[32] * rz;
    float sz = p[33] * rx + p[34] * ry + p[35] * rz;
    float gx = p[36] * sx + p[37] * sy + p[38] * sz + p[45];
    float gy = p[39] * sx + p[40] * sy + p[41] * sz + p[46];
    float gz = p[42] * sx + p[43] * sy + p[44] * sz + p[47];

    const float offx = (-54.0f + 0.15f) - 0.15f;
    const float offy = (-54.0f + 0.15f) - 0.15f;
    const float offz = -10.0f;
    int cx = (int)((gx - offx) / 0.3f);
    int cy = (int)((gy - offy) / 0.3f);
    int cz = (int)((gz - offz) / 20.0f);
    bool kept = (cx >= 0) & (cx < NXV) & (cy >= 0) & (cy < NYV) &
                (cz >= 0) & (cz < 1);
    return kept ? (cx * NYV + cy) : -1;
}

// count with wave-aggregated atomics: ballot-cluster equal voxels, leader adds
__global__ __launch_bounds__(BLK) void geom_count_kernel(
        const float* __restrict__ P, int* __restrict__ cnt) {
    int gid = blockIdx.x * BLK + threadIdx.x;
    int lane = threadIdx.x & 63;
    int vox = point_voxel(P, gid);
    unsigned long long active = __ballot(vox >= 0);
    while (active) {
        int leader = __ffsll((long long)active) - 1;
        int lvox = __shfl(vox, leader);
        unsigned long long match = __ballot(vox == lvox) & active;
        if (lane == leader) atomicAdd(&cnt[lvox], __popcll(match));
        active &= ~match;
    }
}

// ---- exclusive scan of cnt[NVOX] into cursor[NVOX] (3 kernels) ----
__global__ __launch_bounds__(256) void scan1_kernel(
        const int* __restrict__ cnt, int* __restrict__ cursor,
        int* __restrict__ bsum) {
    __shared__ int sh[256];
    int tid = threadIdx.x;
    int i = blockIdx.x * 256 + tid;
    int v = (i < NVOX) ? cnt[i] : 0;
    sh[tid] = v;
    __syncthreads();
    for (int o = 1; o < 256; o <<= 1) {
        int t = (tid >= o) ? sh[tid - o] : 0;
        __syncthreads();
        sh[tid] += t;
        __syncthreads();
    }
    int incl = sh[tid];
    if (i < NVOX) cursor[i] = incl - v;
    if (tid == 255) bsum[blockIdx.x] = incl;
}

__global__ __launch_bounds__(512) void scan2_kernel(int* __restrict__ bsum) {
    __shared__ int sh[512];
    int tid = threadIdx.x;
    int v = (tid < SCAN_BLOCKS) ? bsum[tid] : 0;
    sh[tid] = v;
    __syncthreads();
    for (int o = 1; o < 512; o <<= 1) {
        int t = (tid >= o) ? sh[tid - o] : 0;
        __syncthreads();
        sh[tid] += t;
        __syncthreads();
    }
    if (tid < SCAN_BLOCKS) bsum[tid] = sh[tid] - v;  // exclusive
}

__global__ __launch_bounds__(256) void scan3_kernel(
        int* __restrict__ cursor, const int* __restrict__ bsum) {
    int i = blockIdx.x * 256 + threadIdx.x;
    if (i < NVOX) cursor[i] += bsum[blockIdx.x];
}

// ---- segment worklist for ALL non-empty voxels; <=SEG points per segment.
// w-flag: 0 = sole segment of its voxel (plain store), 1 = shared (atomic).
__global__ __launch_bounds__(256) void buildsegs_kernel(
        const int* __restrict__ cnt, const int* __restrict__ cursor,
        int* __restrict__ nseg, int4* __restrict__ segs) {
    int v = blockIdx.x * 256 + threadIdx.x;
    if (v >= NVOX) return;
    int c = cnt[v];
    if (c == 0) return;
    int ns = (c + SEG - 1) / SEG;
    int base = atomicAdd(nseg, ns);
    int off0 = cursor[v];
    int hv = (c > SEG) ? 1 : 0;
    for (int k = 0; k < ns; k++) {
        if (base + k < MAX_SEGS) {
            int len = min(SEG, c - k * SEG);
            segs[base + k] = make_int4(v, off0 + k * SEG, len, hv);
        }
    }
}

// ---- fill CSR with wave-aggregated cursor atomics ----
__global__ __launch_bounds__(BLK) void fill_kernel(
        const float* __restrict__ P, int* __restrict__ cursor,
        int* __restrict__ idx) {
    int gid = blockIdx.x * BLK + threadIdx.x;
    int lane = threadIdx.x & 63;
    int vox = point_voxel(P, gid);
    unsigned long long lt = (lane == 0) ? 0ull : (~0ull >> (64 - lane));
    unsigned long long active = __ballot(vox >= 0);
    while (active) {
        int leader = __ffsll((long long)active) - 1;
        int lvox = __shfl(vox, leader);
        unsigned long long match = __ballot(vox == lvox) & active;
        int base = 0;
        if (lane == leader) base = atomicAdd(&cursor[lvox], __popcll(match));
        base = __shfl(base, leader);
        if ((match >> lane) & 1ull) {
            int rank = __popcll(match & lt);
            idx[base + rank] = gid;
        }
        active &= ~match;
    }
}

// ---- gather: grid-stride, one wave per segment; lanes own channels.
// idx for the whole segment loaded once (coalesced), broadcast via shfl.
__global__ __launch_bounds__(256) void gather_kernel(
        const float* __restrict__ feats,
        const int* __restrict__ nseg,
        const int4* __restrict__ segs,
        const int* __restrict__ idx,
        float* __restrict__ out) {
    int lane = threadIdx.x & 63;
    int wid = (blockIdx.x * 256 + threadIdx.x) >> 6;
    int nwaves = gridDim.x * 4;
    int n = *nseg;
    if (n > MAX_SEGS) n = MAX_SEGS;

    for (int s = wid; s < n; s += nwaves) {
        int4 sg = segs[s];
        int vox = sg.x, start = sg.y, len = sg.z, heavy = sg.w;
        int pt_l = (lane < len) ? idx[start + lane] : 0;
        float a0 = 0.f, a1 = 0.f;
        int j = 0;
        for (; j + 4 <= len; j += 4) {
            int p0 = __shfl(pt_l, j);
            int p1 = __shfl(pt_l, j + 1);
            int p2 = __shfl(pt_l, j + 2);
            int p3 = __shfl(pt_l, j + 3);
            const float* r0 = feats + (size_t)p0 * CC;
            const float* r1 = feats + (size_t)p1 * CC;
            const float* r2 = feats + (size_t)p2 * CC;
            const float* r3 = feats + (size_t)p3 * CC;
            float x0 = r0[lane], x1 = r1[lane], x2 = r2[lane], x3 = r3[lane];
            float y0 = 0.f, y1 = 0.f, y2 = 0.f, y3 = 0.f;
            if (lane < 16) {
                y0 = r0[64 + lane]; y1 = r1[64 + lane];
                y2 = r2[64 + lane]; y3 = r3[64 + lane];
            }
            a0 += (x0 + x1) + (x2 + x3);
            a1 += (y0 + y1) + (y2 + y3);
        }
        for (; j < len; ++j) {
            int p0 = __shfl(pt_l, j);
            const float* r0 = feats + (size_t)p0 * CC;
            a0 += r0[lane];
            if (lane < 16) a1 += r0[64 + lane];
        }
        float* o0 = out + (size_t)lane * NVOX + vox;
        float* o1 = out + (size_t)(64 + lane) * NVOX + vox;
        if (heavy) {
            atomicAdd(o0, a0);
            if (lane < 16) atomicAdd(o1, a1);
        } else {
            *o0 = a0;
            if (lane < 16) *o1 = a1;
        }
    }
}

extern "C" void kernel_launch(void* const* d_in, const int* in_sizes, int n_in,
                              void* d_out, int out_size, void* d_ws, size_t ws_size,
                              hipStream_t stream) {
    const float* feats = (const float*)d_in[0];
    const float* c2e   = (const float*)d_in[1];
    const float* l2e   = (const float*)d_in[2];
    const float* intr  = (const float*)d_in[3];
    const float* aug   = (const float*)d_in[4];
    const float* laug  = (const float*)d_in[5];
    float* out = (float*)d_out;

    char* ws = (char*)d_ws;
    float* P      = (float*)(ws + WS_P);
    int*   cnt    = (int*)(ws + WS_CNT);
    int*   nseg   = (int*)(ws + WS_NSEG);
    int*   cursor = (int*)(ws + WS_CURSOR);
    int*   bsum   = (int*)(ws + WS_BSUM);
    int4*  segs   = (int4*)(ws + WS_SEGS);
    int*   idx    = (int*)(ws + WS_IDX);

    hipMemsetAsync(cnt, 0, NVOX * 4 + 16, stream);  // cnt + nseg
    hipMemsetAsync(out, 0, (size_t)out_size * sizeof(float), stream);
    precomp_kernel<<<1, 64, 0, stream>>>(c2e, l2e, intr, aug, laug, P);
    geom_count_kernel<<<NPT_BLOCKS, BLK, 0, stream>>>(P, cnt);
    scan1_kernel<<<SCAN_BLOCKS, 256, 0, stream>>>(cnt, cursor, bsum);
    scan2_kernel<<<1, 512, 0, stream>>>(bsum);
    scan3_kernel<<<SCAN_BLOCKS, 256, 0, stream>>>(cursor, bsum);
    buildsegs_kernel<<<SCAN_BLOCKS, 256, 0, stream>>>(cnt, cursor, nseg, segs);
    fill_kernel<<<NPT_BLOCKS, BLK, 0, stream>>>(P, cursor, idx);
    gather_kernel<<<4096, 256, 0, stream>>>(feats, nseg, segs, idx, out);
}